// Round 1
// 494.392 us; speedup vs baseline: 1.0638x; 1.0638x over previous
//
#include <hip/hip_runtime.h>
#include <stdint.h>

#define N_ROWS 16384
#define K_DIM  2048
#define N_OUT  2048
#define NGROUPS 8
#define BM 256
#define BN 256
#define BK 64
#define MAX_Y 72   // sum ceil(n_g/256) <= 16384/256 + 8

typedef short s16x8 __attribute__((ext_vector_type(8)));   // 8 bf16 bit-patterns
typedef float f32x4 __attribute__((ext_vector_type(4)));

// RNE float -> bf16 (bit-level)
__device__ __forceinline__ unsigned short f2bf(float f) {
    unsigned int u = __float_as_uint(f);
    u += 0x7fffu + ((u >> 16) & 1u);
    return (unsigned short)(u >> 16);
}

__global__ void convert_kernel(const float* __restrict__ src,
                               unsigned short* __restrict__ dst, int n) {
    int stride = gridDim.x * blockDim.x;
    for (int i = blockIdx.x * blockDim.x + threadIdx.x; i * 4 < n; i += stride) {
        float4 v = *(const float4*)(src + (size_t)i * 4);
        ushort4 o;
        o.x = f2bf(v.x); o.y = f2bf(v.y); o.z = f2bf(v.z); o.w = f2bf(v.w);
        *(ushort4*)(dst + (size_t)i * 4) = o;
    }
}

__device__ __forceinline__ int lower_bound_g(const int* __restrict__ gi, int g) {
    int lo = 0, hi = N_ROWS;
    while (lo < hi) { int mid = (lo + hi) >> 1; if (gi[mid] < g) lo = mid + 1; else hi = mid; }
    return lo;
}

#define GLDS16(gp, lp) \
    __builtin_amdgcn_global_load_lds((__attribute__((address_space(1))) void*)(gp), \
                                     (__attribute__((address_space(3))) void*)(lp), 16, 0, 0)

#define VMW(N)  asm volatile("s_waitcnt vmcnt(" #N ")" ::: "memory")
#define BAR()   asm volatile("s_barrier" ::: "memory")
#define LGKM0() do { asm volatile("s_waitcnt lgkmcnt(0)" ::: "memory"); \
                     __builtin_amdgcn_sched_barrier(0); } while (0)

// ---------------------------------------------------------------------------
// 256x256x64 8-phase grouped GEMM (T2 swizzle + T3/T4 counted vmcnt + T5).
// LDS: A = [2 buf][2 khalf][256 rows][32 k] bf16 (16 KB blocks), B same at +64K.
// Read swizzle: 16B slot ^= (row>>1)&3  (inverse applied on global source;
// global_load_lds dest stays linear — both-sides-or-neither, rule #21).
// Stage order per tile: A-ks0, B-ks0, A-ks1, B-ks1. Steady state keeps
// 3 half-tiles (6 loads) in flight; vmcnt(6) at phases 4/8 only.
// ---------------------------------------------------------------------------
__global__ __launch_bounds__(512, 2) void grouped_gemm(
    const unsigned short* __restrict__ xb,   // [N, K] bf16
    const unsigned short* __restrict__ wb,   // [G, N_OUT, K] bf16
    const float* __restrict__ bias,          // [G, N_OUT] fp32
    const int* __restrict__ gi,              // sorted [N]
    float* __restrict__ out)                 // [N, N_OUT] fp32
{
    __shared__ unsigned char lds[131072];
    __shared__ int sh_s[NGROUPS + 1];

    const int t5 = threadIdx.x;

    // Parallel group-boundary search: one boundary per thread (14 dependent
    // loads of latency instead of 8*14), broadcast through LDS.
    if (t5 <= NGROUPS)
        sh_s[t5] = (t5 == 0) ? 0 : (t5 == NGROUPS ? N_ROWS : lower_bound_g(gi, t5));
    __syncthreads();

    int by = blockIdx.y;
    int row0 = -1, g = 0, nrows = 0, c = 0;
    #pragma unroll
    for (int gg = 0; gg < NGROUPS; gg++) {
        int n = sh_s[gg + 1] - sh_s[gg];
        int tiles = (n + BM - 1) >> 8;
        if (row0 < 0 && by < c + tiles) {
            g = gg;
            row0 = sh_s[gg] + (by - c) * BM;
            nrows = n - (by - c) * BM; if (nrows > BM) nrows = BM;
        }
        c += tiles;
    }
    if (row0 < 0) return;   // uniform early-out (after the only __syncthreads)
    int col0 = blockIdx.x * BN;

    // ---- staging setup: thread t covers (row = j*128 + t/4, 16B slot = t&3) ----
    int rsub = t5 >> 2;                       // 0..127
    int swz  = (t5 & 3) ^ ((rsub >> 1) & 3);  // inverse swizzle on SOURCE slot
    int ar0 = min(row0 + rsub,       N_ROWS - 1);   // clamp partial tiles
    int ar1 = min(row0 + 128 + rsub, N_ROWS - 1);
    const unsigned short* srcA0 = xb + (size_t)ar0 * K_DIM + swz * 8;
    const unsigned short* srcA1 = xb + (size_t)ar1 * K_DIM + swz * 8;
    const unsigned short* srcB0 = wb + ((size_t)g * N_OUT + col0 + rsub) * K_DIM + swz * 8;
    const unsigned short* srcB1 = srcB0 + (size_t)128 * K_DIM;
    char* ldsA = (char*)lds;
    char* ldsB = (char*)lds + 65536;
    char* dA = ldsA + t5 * 16;     // + buf*32768 + khalf*16384 (+8192 for j=1)
    char* dB = ldsB + t5 * 16;

#define STAGE_A(BUF,H,KT) do { \
    GLDS16(srcA0 + (KT)*64 + (H)*32, dA + (BUF)*32768 + (H)*16384); \
    GLDS16(srcA1 + (KT)*64 + (H)*32, dA + (BUF)*32768 + (H)*16384 + 8192); } while (0)
#define STAGE_B(BUF,H,KT) do { \
    GLDS16(srcB0 + (KT)*64 + (H)*32, dB + (BUF)*32768 + (H)*16384); \
    GLDS16(srcB1 + (KT)*64 + (H)*32, dB + (BUF)*32768 + (H)*16384 + 8192); } while (0)

    // ---- fragment-read setup (wave layout 2M x 4N, per-wave 128x64 of C) ----
    int w = t5 >> 6, l = t5 & 63, la = l & 15, q = l >> 4;
    int wm = w >> 2, wn = w & 3;
    // swizzled read slot: (q ^ ((row>>1)&3)); row steps of 16/64/128 keep
    // (row>>1)&3 invariant, so it reduces to la only -> fold into one base.
    int swr   = (q ^ ((la >> 1) & 3)) * 16;
    int aOff0 = (wm * 128 + la) * 64 + swr;
    int bOff0 = (wn * 64  + la) * 64 + swr;

#define RDA8(DST, BUF, KS) do { _Pragma("unroll") \
    for (int mi = 0; mi < 8; mi++) \
        DST[mi] = *(const s16x8*)(ldsA + (BUF)*32768 + (KS)*16384 + aOff0 + mi*1024); } while (0)
#define RDB1(DST, BUF, KS, NI) \
    DST = *(const s16x8*)(ldsB + (BUF)*32768 + (KS)*16384 + bOff0 + (NI)*1024)

    f32x4 acc[8][4];
    #pragma unroll
    for (int i2 = 0; i2 < 8; i2++)
        #pragma unroll
        for (int j2 = 0; j2 < 4; j2++)
            acc[i2][j2] = (f32x4){0.f, 0.f, 0.f, 0.f};

    s16x8 a0[8], a1[8], b0[4], b1[4];

#define MFMA16(AF, BL, BH, N0, N1) do { \
    __builtin_amdgcn_s_setprio(1); \
    _Pragma("unroll") for (int mi = 0; mi < 8; mi++) { \
        acc[mi][N0] = __builtin_amdgcn_mfma_f32_16x16x32_bf16(AF[mi], BL, acc[mi][N0], 0, 0, 0); \
        acc[mi][N1] = __builtin_amdgcn_mfma_f32_16x16x32_bf16(AF[mi], BH, acc[mi][N1], 0, 0, 0); } \
    __builtin_amdgcn_s_setprio(0); } while (0)

// One K-tile = 4 phases. Per phase: ds_reads -> stage issue -> [vmcnt] ->
// barrier -> lgkmcnt(0) -> 16 MFMA -> barrier. Reads: P1 a0+b0lo, P2 b0hi,
// P3 a1+b1lo, P4 b1hi (keeps frag regs ~190 live, under the 256 cap).
#define QTILE(BUF, ST1, ST2, ST3, ST4, W4) do { \
    RDA8(a0, BUF, 0); RDB1(b0[0], BUF, 0, 0); RDB1(b0[1], BUF, 0, 1); \
    ST1; BAR(); LGKM0(); MFMA16(a0, b0[0], b0[1], 0, 1); BAR(); \
    RDB1(b0[2], BUF, 0, 2); RDB1(b0[3], BUF, 0, 3); \
    ST2; BAR(); LGKM0(); MFMA16(a0, b0[2], b0[3], 2, 3); BAR(); \
    RDA8(a1, BUF, 1); RDB1(b1[0], BUF, 1, 0); RDB1(b1[1], BUF, 1, 1); \
    ST3; BAR(); LGKM0(); MFMA16(a1, b1[0], b1[1], 0, 1); BAR(); \
    RDB1(b1[2], BUF, 1, 2); RDB1(b1[3], BUF, 1, 3); \
    ST4; W4; BAR(); LGKM0(); MFMA16(a1, b1[2], b1[3], 2, 3); BAR(); \
} while (0)

    // Prologue: tile0 (buf0) fully + tile1 (buf1) A0,B0,A1. vmcnt(6) leaves
    // exactly those 3 half-tiles in flight with tile0 landed.
    STAGE_A(0,0,0); STAGE_B(0,0,0); STAGE_A(0,1,0); STAGE_B(0,1,0);
    STAGE_A(1,0,1); STAGE_B(1,0,1); STAGE_A(1,1,1);
    VMW(6);
    BAR();

    // Main loop: 15 iterations x 2 K-tiles (tiles 0..29 of 32).
    // Stage slots target only regions whose last ds_read was in a prior phase
    // (region-deadness verified per phase); vmcnt(6) at P4/P8 guarantees the
    // next tile is fully in LDS before its first read.
    #pragma unroll 1
    for (int i = 0; i < 15; i++) {
        int kt0 = 2 * i + 2, kt1 = 2 * i + 3, ktp = 2 * i + 1;
        QTILE(0, STAGE_B(1,1,ktp), STAGE_A(0,0,kt0), STAGE_B(0,0,kt0),
                 STAGE_A(0,1,kt0), VMW(6));
        QTILE(1, STAGE_B(0,1,kt0), STAGE_A(1,0,kt1), STAGE_B(1,0,kt1),
                 STAGE_A(1,1,kt1), VMW(6));
    }
    // Tail pair (tiles 30,31): finish tile31's B-ks1, drain with vmcnt(0).
    QTILE(0, STAGE_B(1,1,31), ((void)0), ((void)0), ((void)0), VMW(0));
    QTILE(1, ((void)0), ((void)0), ((void)0), ((void)0), ((void)0));

    // Epilogue: C/D layout col=lane&15, row=quad*4+reg (m89/m91-verified); fused bias.
    int row_end = row0 + nrows;
    float bv[4];
    #pragma unroll
    for (int ni = 0; ni < 4; ni++)
        bv[ni] = bias[g * N_OUT + col0 + wn * 64 + ni * 16 + la];
    #pragma unroll
    for (int mi = 0; mi < 8; mi++) {
        int rbase = row0 + wm * 128 + mi * 16 + q * 4;
        #pragma unroll
        for (int r = 0; r < 4; r++) {
            int row = rbase + r;
            if (row < row_end) {
                float* op = out + (size_t)row * N_OUT + col0 + wn * 64 + la;
                #pragma unroll
                for (int ni = 0; ni < 4; ni++)
                    op[ni * 16] = acc[mi][ni][r] + bv[ni];
            }
        }
    }
}

// Last-resort fallback (ws too small for bf16 copies): correct fp32 path.
__global__ void naive_kernel(const float* __restrict__ x, const float* __restrict__ wgt,
                             const float* __restrict__ bias, const int* __restrict__ gi,
                             float* __restrict__ out) {
    int row = blockIdx.x;
    int g = gi[row] & (NGROUPS - 1);
    __shared__ float xs[K_DIM];
    for (int i = threadIdx.x; i < K_DIM; i += 256) xs[i] = x[(size_t)row * K_DIM + i];
    __syncthreads();
    for (int c = threadIdx.x; c < N_OUT; c += 256) {
        const float* wr = wgt + ((size_t)g * N_OUT + c) * K_DIM;
        float s = 0.f;
        for (int k = 0; k < K_DIM; k++) s += xs[k] * wr[k];
        out[(size_t)row * N_OUT + c] = s + bias[g * N_OUT + c];
    }
}

extern "C" void kernel_launch(void* const* d_in, const int* in_sizes, int n_in,
                              void* d_out, int out_size, void* d_ws, size_t ws_size,
                              hipStream_t stream) {
    const float* x    = (const float*)d_in[0];
    const float* wgt  = (const float*)d_in[1];
    const float* bias = (const float*)d_in[2];
    const int*   gi   = (const int*)d_in[3];
    float* out = (float*)d_out;

    const size_t xb_bytes = (size_t)N_ROWS * K_DIM * 2;           // 64 MiB
    const size_t wb_bytes = (size_t)NGROUPS * N_OUT * K_DIM * 2;  // 64 MiB
    const size_t need = xb_bytes + wb_bytes;                      // exactly 128 MiB

    if (ws_size < need) {
        naive_kernel<<<dim3(N_ROWS), dim3(256), 0, stream>>>(x, wgt, bias, gi, out);
        return;
    }

    unsigned short* xb = (unsigned short*)d_ws;
    unsigned short* wb = (unsigned short*)((char*)d_ws + xb_bytes);

    convert_kernel<<<dim3(8192), dim3(256), 0, stream>>>(x,   xb, N_ROWS * K_DIM);
    convert_kernel<<<dim3(8192), dim3(256), 0, stream>>>(wgt, wb, NGROUPS * N_OUT * K_DIM);
    grouped_gemm<<<dim3(N_OUT / BN, MAX_Y), dim3(512), 0, stream>>>(
        xb, wb, bias, gi, out);
}